// Round 3
// baseline (5791.696 us; speedup 1.0000x reference)
//
#include <hip/hip_runtime.h>

// B=4, S=2048, D=1024, H=16, Dh=64.  M = B*S = 8192, K = N = 1024.

typedef __attribute__((ext_vector_type(8))) short short8;
typedef __attribute__((ext_vector_type(4))) float floatx4;
typedef __attribute__((ext_vector_type(4))) unsigned short ushortx4;
typedef __attribute__((ext_vector_type(4))) unsigned int uintx4;

#define MFMA_BF16(a, b, c) __builtin_amdgcn_mfma_f32_16x16x32_bf16((a), (b), (c), 0, 0, 0)

__device__ __forceinline__ unsigned short f2bf(float f) {
  unsigned int u = __builtin_bit_cast(unsigned int, f);
  u += 0x7FFFu + ((u >> 16) & 1u);   // RNE
  return (unsigned short)(u >> 16);
}
__device__ __forceinline__ float bf2f(unsigned short b) {
  return __builtin_bit_cast(float, (unsigned int)b << 16);
}
__device__ __forceinline__ floatx4 fzero4() {
  floatx4 v; v[0] = 0.f; v[1] = 0.f; v[2] = 0.f; v[3] = 0.f; return v;
}

// ---------- weight conversion: 4 x [1024x1024] f32 -> bf16 (contiguous dst) ----------
__global__ __launch_bounds__(256) void cvtw_kernel(
    const float* __restrict__ w0, const float* __restrict__ w1,
    const float* __restrict__ w2, const float* __restrict__ w3,
    unsigned short* __restrict__ dst) {
  int tid = blockIdx.x * 256 + threadIdx.x;     // 524288 threads, 8 elems each
  int seg = tid >> 17;
  int off = (tid & 0x1FFFF) << 3;
  const float* src = seg == 0 ? w0 : seg == 1 ? w1 : seg == 2 ? w2 : w3;
  floatx4 a = *reinterpret_cast<const floatx4*>(src + off);
  floatx4 b = *reinterpret_cast<const floatx4*>(src + off + 4);
  ushortx4 r0, r1;
#pragma unroll
  for (int i = 0; i < 4; ++i) { r0[i] = f2bf(a[i]); r1[i] = f2bf(b[i]); }
  unsigned short* d = dst + ((size_t)seg << 20) + off;
  *reinterpret_cast<ushortx4*>(d) = r0;
  *reinterpret_cast<ushortx4*>(d + 4) = r1;
}

// ---------- NT GEMM: C[m,n] = sum_k A[m,k]*W[n,k] + bias[n] ----------
// 128x128 tile, BK=64, 4 waves (2x2), each wave 64x64 via 4x4 16x16x32 frags.
// LDS: padded rows [128][72] (144B stride: 16B-aligned, no swizzle).
// epi 0: dst bf16 [B,H,S,64]   (Q,K,V head-split)
// epi 2: dst f32  [M,1024]     (final output)
template<bool AF32>
__global__ __launch_bounds__(256, 2) void gemm128_kernel(
    const void* __restrict__ Aptr, const unsigned short* __restrict__ Bw,
    const float* __restrict__ bias, void* __restrict__ Cptr, int epi) {
  __shared__ __align__(16) unsigned short As[128][72];
  __shared__ __align__(16) unsigned short Bs[128][72];
  const int tid = threadIdx.x;
  const int l = tid & 63, wv = tid >> 6;
  const int lo = l & 15, g = l >> 4;
  const int wr = wv >> 1, wc = wv & 1;
  const int m0 = blockIdx.x * 128, n0 = blockIdx.y * 128;

  floatx4 acc[4][4];
#pragma unroll
  for (int mi = 0; mi < 4; ++mi)
#pragma unroll
    for (int ni = 0; ni < 4; ++ni) acc[mi][ni] = fzero4();

  for (int k0 = 0; k0 < 1024; k0 += 64) {
    __syncthreads();
    if constexpr (AF32) {
      const float* A = (const float*)Aptr;
#pragma unroll
      for (int i = 0; i < 8; ++i) {
        int c = i * 256 + tid;          // 2048 groups of 4 f32
        int row = c >> 4, c4 = c & 15;
        floatx4 v = *reinterpret_cast<const floatx4*>(A + (size_t)(m0 + row) * 1024 + k0 + c4 * 4);
        ushortx4 pk;
#pragma unroll
        for (int e = 0; e < 4; ++e) pk[e] = f2bf(v[e]);
        *reinterpret_cast<ushortx4*>(&As[row][c4 * 4]) = pk;
      }
    } else {
      const unsigned short* A = (const unsigned short*)Aptr;
#pragma unroll
      for (int i = 0; i < 4; ++i) {
        int c = i * 256 + tid;          // 1024 16B chunks
        int row = c >> 3, ch = c & 7;
        uintx4 v = *reinterpret_cast<const uintx4*>(A + (size_t)(m0 + row) * 1024 + k0 + ch * 8);
        *reinterpret_cast<uintx4*>(&As[row][ch * 8]) = v;
      }
    }
#pragma unroll
    for (int i = 0; i < 4; ++i) {       // stage B (bf16 weights, rows = n)
      int c = i * 256 + tid;
      int row = c >> 3, ch = c & 7;
      uintx4 v = *reinterpret_cast<const uintx4*>(Bw + (size_t)(n0 + row) * 1024 + k0 + ch * 8);
      *reinterpret_cast<uintx4*>(&Bs[row][ch * 8]) = v;
    }
    __syncthreads();

    short8 af[4][2], bf[4][2];
#pragma unroll
    for (int mi = 0; mi < 4; ++mi)
#pragma unroll
      for (int ks = 0; ks < 2; ++ks)
        af[mi][ks] = *reinterpret_cast<const short8*>(&As[wr * 64 + mi * 16 + lo][ks * 32 + g * 8]);
#pragma unroll
    for (int ni = 0; ni < 4; ++ni)
#pragma unroll
      for (int ks = 0; ks < 2; ++ks)
        bf[ni][ks] = *reinterpret_cast<const short8*>(&Bs[wc * 64 + ni * 16 + lo][ks * 32 + g * 8]);
#pragma unroll
    for (int ks = 0; ks < 2; ++ks)
#pragma unroll
      for (int mi = 0; mi < 4; ++mi)
#pragma unroll
        for (int ni = 0; ni < 4; ++ni)
          acc[mi][ni] = MFMA_BF16(af[mi][ks], bf[ni][ks], acc[mi][ni]);
  }

  // epilogue: D frag layout col = lane&15 (n), row = (lane>>4)*4 + reg (m)
#pragma unroll
  for (int mi = 0; mi < 4; ++mi) {
    const int mrow = m0 + wr * 64 + mi * 16 + 4 * g;   // + reg r
    const int b = mrow >> 11, s = mrow & 2047;
#pragma unroll
    for (int ni = 0; ni < 4; ++ni) {
      const int n = n0 + wc * 64 + ni * 16 + lo;
      const float bn = bias[n];
      if (epi == 0) {
        unsigned short* dst = (unsigned short*)Cptr;
        const int h = n >> 6, dh = n & 63;
#pragma unroll
        for (int r = 0; r < 4; ++r)
          dst[((size_t)(b * 16 + h) * 2048 + s + r) * 64 + dh] = f2bf(acc[mi][ni][r] + bn);
      } else {
        float* dst = (float*)Cptr;
#pragma unroll
        for (int r = 0; r < 4; ++r)
          dst[(size_t)(mrow + r) * 1024 + n] = acc[mi][ni][r] + bn;
      }
    }
  }
}

// ---------- scalar flash attention (diagnostic: no MFMA, no fragment layouts) ----------
// One wave per q-row. Lane j computes score for column j0+j; lane d accumulates
// output dim d. P broadcast through per-wave LDS. Q,K,V: [B,H,S,64] bf16.
__global__ __launch_bounds__(256) void attn_scalar_kernel(
    const unsigned short* __restrict__ Qh, const unsigned short* __restrict__ Kh,
    const unsigned short* __restrict__ Vh, unsigned short* __restrict__ O) {
  __shared__ float Ps[4][64];
  const int tid = threadIdx.x;
  const int wv = tid >> 6, lane = tid & 63;
  const int w = blockIdx.x * 4 + wv;          // global wave id = q-row id
  const int bh = w >> 11, srow = w & 2047;    // 2048 rows per (b,h); %4==0 so block shares bh
  const int b = bh >> 4, h = bh & 15;
  const unsigned short* Q = Qh + ((size_t)bh * 2048 + srow) * 64;
  const unsigned short* K = Kh + (size_t)bh * (2048 * 64);
  const unsigned short* V = Vh + (size_t)bh * (2048 * 64);
  const float SC = 0.18033688011110793f;  // log2(e)/sqrt(64)

  float q[64];
#pragma unroll
  for (int c = 0; c < 8; ++c) {
    short8 q8 = *reinterpret_cast<const short8*>(Q + c * 8);   // uniform: broadcast
#pragma unroll
    for (int e = 0; e < 8; ++e) q[c * 8 + e] = bf2f((unsigned short)q8[e]);
  }

  float m = -1e30f, l = 0.f, acc = 0.f;
  for (int j0 = 0; j0 < 2048; j0 += 64) {
    // ---- score for column (j0 + lane) ----
    float s = 0.f;
    const unsigned short* kp = K + (size_t)(j0 + lane) * 64;
#pragma unroll
    for (int c = 0; c < 8; ++c) {
      short8 k8 = *reinterpret_cast<const short8*>(kp + c * 8);
#pragma unroll
      for (int e = 0; e < 8; ++e) s = fmaf(q[c * 8 + e], bf2f((unsigned short)k8[e]), s);
    }
    const float sm = s * SC;     // log2 domain
    // ---- full-wave online softmax ----
    float mx = sm;
#pragma unroll
    for (int off = 32; off; off >>= 1) mx = fmaxf(mx, __shfl_xor(mx, off));
    const float nm = fmaxf(m, mx);
    const float cf = exp2f(m - nm);
    m = nm;
    const float p = exp2f(sm - nm);
    float ls = p;
#pragma unroll
    for (int off = 32; off; off >>= 1) ls += __shfl_xor(ls, off);
    l = l * cf + ls;
    Ps[wv][lane] = p;            // same-wave RAW; compiler orders LDS ops
    // ---- PV: lane owns output dim d = lane ----
    acc *= cf;
#pragma unroll 16
    for (int j = 0; j < 64; ++j)
      acc = fmaf(Ps[wv][j], bf2f(V[(size_t)(j0 + j) * 64 + lane]), acc);
  }

  O[((size_t)b * 2048 + srow) * 1024 + h * 64 + lane] = f2bf(acc / l);
}

extern "C" void kernel_launch(void* const* d_in, const int* in_sizes, int n_in,
                              void* d_out, int out_size, void* d_ws, size_t ws_size,
                              hipStream_t stream) {
  (void)in_sizes; (void)n_in; (void)out_size; (void)ws_size;
  const float* query = (const float*)d_in[0];
  const float* key_  = (const float*)d_in[1];
  const float* value = (const float*)d_in[2];
  const float* Wq = (const float*)d_in[3];
  const float* bq = (const float*)d_in[4];
  const float* Wk = (const float*)d_in[5];
  const float* bk = (const float*)d_in[6];
  const float* Wv = (const float*)d_in[7];
  const float* bv = (const float*)d_in[8];
  const float* Wo = (const float*)d_in[9];
  const float* bo = (const float*)d_in[10];

  unsigned short* ws = (unsigned short*)d_ws;
  unsigned short* Wq_bf = ws;                              // 1M elems each, contiguous
  unsigned short* Wk_bf = ws + ((size_t)1 << 20);
  unsigned short* Wv_bf = ws + ((size_t)2 << 20);
  unsigned short* Wo_bf = ws + ((size_t)3 << 20);
  unsigned short* Qh = ws + ((size_t)4 << 20);             // [4,16,2048,64] bf16
  unsigned short* Kh = Qh + ((size_t)8 << 20);
  unsigned short* Vh = Kh + ((size_t)8 << 20);             // [4,16,2048,64]
  unsigned short* Oa = Vh + ((size_t)8 << 20);             // [4,2048,1024]

  cvtw_kernel<<<2048, 256, 0, stream>>>(Wq, Wk, Wv, Wo, Wq_bf);
  dim3 gg(64, 8);
  gemm128_kernel<true><<<gg, 256, 0, stream>>>(query, Wq_bf, bq, Qh, 0);
  gemm128_kernel<true><<<gg, 256, 0, stream>>>(key_,  Wk_bf, bk, Kh, 0);
  gemm128_kernel<true><<<gg, 256, 0, stream>>>(value, Wv_bf, bv, Vh, 0);
  attn_scalar_kernel<<<32768, 256, 0, stream>>>(Qh, Kh, Vh, Oa);
  gemm128_kernel<false><<<gg, 256, 0, stream>>>(Oa, Wo_bf, bo, d_out, 2);
}

// Round 4
// 1381.619 us; speedup vs baseline: 4.1920x; 4.1920x over previous
//
#include <hip/hip_runtime.h>

// B=4, S=2048, D=1024, H=16, Dh=64.  M = B*S = 8192, K = N = 1024.

typedef __attribute__((ext_vector_type(8))) short short8;
typedef __attribute__((ext_vector_type(4))) float floatx4;
typedef __attribute__((ext_vector_type(4))) unsigned short ushortx4;
typedef __attribute__((ext_vector_type(4))) unsigned int uintx4;

#define MFMA_BF16(a, b, c) __builtin_amdgcn_mfma_f32_16x16x32_bf16((a), (b), (c), 0, 0, 0)

__device__ __forceinline__ unsigned short f2bf(float f) {
  unsigned int u = __builtin_bit_cast(unsigned int, f);
  u += 0x7FFFu + ((u >> 16) & 1u);   // RNE
  return (unsigned short)(u >> 16);
}
__device__ __forceinline__ float bf2f(unsigned short b) {
  return __builtin_bit_cast(float, (unsigned int)b << 16);
}
__device__ __forceinline__ floatx4 fzero4() {
  floatx4 v; v[0] = 0.f; v[1] = 0.f; v[2] = 0.f; v[3] = 0.f; return v;
}

// ---------- weight conversion: 4 x [1024x1024] f32 -> bf16 (contiguous dst) ----------
__global__ __launch_bounds__(256) void cvtw_kernel(
    const float* __restrict__ w0, const float* __restrict__ w1,
    const float* __restrict__ w2, const float* __restrict__ w3,
    unsigned short* __restrict__ dst) {
  int tid = blockIdx.x * 256 + threadIdx.x;     // 524288 threads, 8 elems each
  int seg = tid >> 17;
  int off = (tid & 0x1FFFF) << 3;
  const float* src = seg == 0 ? w0 : seg == 1 ? w1 : seg == 2 ? w2 : w3;
  floatx4 a = *reinterpret_cast<const floatx4*>(src + off);
  floatx4 b = *reinterpret_cast<const floatx4*>(src + off + 4);
  ushortx4 r0, r1;
#pragma unroll
  for (int i = 0; i < 4; ++i) { r0[i] = f2bf(a[i]); r1[i] = f2bf(b[i]); }
  unsigned short* d = dst + ((size_t)seg << 20) + off;
  *reinterpret_cast<ushortx4*>(d) = r0;
  *reinterpret_cast<ushortx4*>(d + 4) = r1;
}

// ---------- NT GEMM: C[m,n] = sum_k A[m,k]*W[n,k] + bias[n] ----------
// 128x128 tile, BK=64, 4 waves (2x2), each wave 64x64 via 4x4 16x16x32 frags.
// LDS: padded rows [128][72] (144B stride: 16B-aligned, no swizzle).
// epi 0: dst bf16 [B,H,S,64]   (Q,K,V head-split)
// epi 2: dst f32  [M,1024]     (final output)
template<bool AF32>
__global__ __launch_bounds__(256, 2) void gemm128_kernel(
    const void* __restrict__ Aptr, const unsigned short* __restrict__ Bw,
    const float* __restrict__ bias, void* __restrict__ Cptr, int epi) {
  __shared__ __align__(16) unsigned short As[128][72];
  __shared__ __align__(16) unsigned short Bs[128][72];
  const int tid = threadIdx.x;
  const int l = tid & 63, wv = tid >> 6;
  const int lo = l & 15, g = l >> 4;
  const int wr = wv >> 1, wc = wv & 1;
  const int m0 = blockIdx.x * 128, n0 = blockIdx.y * 128;

  floatx4 acc[4][4];
#pragma unroll
  for (int mi = 0; mi < 4; ++mi)
#pragma unroll
    for (int ni = 0; ni < 4; ++ni) acc[mi][ni] = fzero4();

  for (int k0 = 0; k0 < 1024; k0 += 64) {
    __syncthreads();
    if constexpr (AF32) {
      const float* A = (const float*)Aptr;
#pragma unroll
      for (int i = 0; i < 8; ++i) {
        int c = i * 256 + tid;          // 2048 groups of 4 f32
        int row = c >> 4, c4 = c & 15;
        floatx4 v = *reinterpret_cast<const floatx4*>(A + (size_t)(m0 + row) * 1024 + k0 + c4 * 4);
        ushortx4 pk;
#pragma unroll
        for (int e = 0; e < 4; ++e) pk[e] = f2bf(v[e]);
        *reinterpret_cast<ushortx4*>(&As[row][c4 * 4]) = pk;
      }
    } else {
      const unsigned short* A = (const unsigned short*)Aptr;
#pragma unroll
      for (int i = 0; i < 4; ++i) {
        int c = i * 256 + tid;          // 1024 16B chunks
        int row = c >> 3, ch = c & 7;
        uintx4 v = *reinterpret_cast<const uintx4*>(A + (size_t)(m0 + row) * 1024 + k0 + ch * 8);
        *reinterpret_cast<uintx4*>(&As[row][ch * 8]) = v;
      }
    }
#pragma unroll
    for (int i = 0; i < 4; ++i) {       // stage B (bf16 weights, rows = n)
      int c = i * 256 + tid;
      int row = c >> 3, ch = c & 7;
      uintx4 v = *reinterpret_cast<const uintx4*>(Bw + (size_t)(n0 + row) * 1024 + k0 + ch * 8);
      *reinterpret_cast<uintx4*>(&Bs[row][ch * 8]) = v;
    }
    __syncthreads();

    short8 af[4][2], bf[4][2];
#pragma unroll
    for (int mi = 0; mi < 4; ++mi)
#pragma unroll
      for (int ks = 0; ks < 2; ++ks)
        af[mi][ks] = *reinterpret_cast<const short8*>(&As[wr * 64 + mi * 16 + lo][ks * 32 + g * 8]);
#pragma unroll
    for (int ni = 0; ni < 4; ++ni)
#pragma unroll
      for (int ks = 0; ks < 2; ++ks)
        bf[ni][ks] = *reinterpret_cast<const short8*>(&Bs[wc * 64 + ni * 16 + lo][ks * 32 + g * 8]);
#pragma unroll
    for (int ks = 0; ks < 2; ++ks)
#pragma unroll
      for (int mi = 0; mi < 4; ++mi)
#pragma unroll
        for (int ni = 0; ni < 4; ++ni)
          acc[mi][ni] = MFMA_BF16(af[mi][ks], bf[ni][ks], acc[mi][ni]);
  }

  // epilogue: D frag layout col = lane&15 (n), row = (lane>>4)*4 + reg (m)
#pragma unroll
  for (int mi = 0; mi < 4; ++mi) {
    const int mrow = m0 + wr * 64 + mi * 16 + 4 * g;   // + reg r
    const int b = mrow >> 11, s = mrow & 2047;
#pragma unroll
    for (int ni = 0; ni < 4; ++ni) {
      const int n = n0 + wc * 64 + ni * 16 + lo;
      const float bn = bias[n];
      if (epi == 0) {
        unsigned short* dst = (unsigned short*)Cptr;
        const int h = n >> 6, dh = n & 63;
#pragma unroll
        for (int r = 0; r < 4; ++r)
          dst[((size_t)(b * 16 + h) * 2048 + s + r) * 64 + dh] = f2bf(acc[mi][ni][r] + bn);
      } else {
        float* dst = (float*)Cptr;
#pragma unroll
        for (int r = 0; r < 4; ++r)
          dst[(size_t)(mrow + r) * 1024 + n] = acc[mi][ni][r] + bn;
      }
    }
  }
}

// ---------- hybrid flash attention (bisect round): MFMA QK^T + softmax, SCALAR PV ----------
// grid: (B*H)*16 blocks; 4 waves; wave owns 32 q-rows; KV blocks of 64.
// Q,K,V: [B,H,S,64] bf16 (epi0, validated). O: [B,S,1024] bf16.
// QK^T/softmax identical to round 2. PV: lane owns dim d=lane; V tile in regs;
// P rows read from Pl as 16B broadcasts; rescale by Cl (cfac) per row.
__global__ __launch_bounds__(256, 2) void attn_hybrid_kernel(
    const unsigned short* __restrict__ Qh, const unsigned short* __restrict__ Kh,
    const unsigned short* __restrict__ Vh, unsigned short* __restrict__ O) {
  __shared__ __align__(16) unsigned short Pl[4][32][72];
  __shared__ float Cl[4][32];
  const int tid = threadIdx.x;
  const int wv = tid >> 6, l = tid & 63, lo = l & 15, g = l >> 4;
  const int bh = blockIdx.x >> 4, qblk = blockIdx.x & 15;
  const unsigned short* Q = Qh + (size_t)bh * (2048 * 64);
  const unsigned short* K = Kh + (size_t)bh * (2048 * 64);
  const unsigned short* V = Vh + (size_t)bh * (2048 * 64);
  const int qbase = qblk * 128 + wv * 32;
  const float SC = 0.18033688011110793f;  // log2(e)/sqrt(64)

  short8 qfr[2][2];  // [qfrag][kd]
#pragma unroll
  for (int qf = 0; qf < 2; ++qf)
#pragma unroll
    for (int kd = 0; kd < 2; ++kd)
      qfr[qf][kd] = *reinterpret_cast<const short8*>(
          Q + (size_t)(qbase + qf * 16 + lo) * 64 + kd * 32 + g * 8);

  float mrun[2][4], lrun[2][4];
#pragma unroll
  for (int qf = 0; qf < 2; ++qf)
#pragma unroll
    for (int r = 0; r < 4; ++r) { mrun[qf][r] = -1e30f; lrun[qf][r] = 0.f; }
  float acc2[32];
#pragma unroll
  for (int i = 0; i < 32; ++i) acc2[i] = 0.f;

  for (int j0 = 0; j0 < 2048; j0 += 64) {
    // ---- QK^T (MFMA): sc[qf][kf], row (g*4+r)=q, col lo=k ----
    floatx4 sc[2][4];
#pragma unroll
    for (int qf = 0; qf < 2; ++qf)
#pragma unroll
      for (int kf = 0; kf < 4; ++kf) sc[qf][kf] = fzero4();
#pragma unroll
    for (int kf = 0; kf < 4; ++kf) {
      const unsigned short* kp = K + (size_t)(j0 + kf * 16 + lo) * 64 + g * 8;
      short8 k0 = *reinterpret_cast<const short8*>(kp);
      short8 k1 = *reinterpret_cast<const short8*>(kp + 32);
#pragma unroll
      for (int qf = 0; qf < 2; ++qf) {
        sc[qf][kf] = MFMA_BF16(qfr[qf][0], k0, sc[qf][kf]);
        sc[qf][kf] = MFMA_BF16(qfr[qf][1], k1, sc[qf][kf]);
      }
    }
    // ---- online softmax (identical to round 2) ----
#pragma unroll
    for (int qf = 0; qf < 2; ++qf) {
      float cfac[4];
#pragma unroll
      for (int r = 0; r < 4; ++r) {
        float mx = fmaxf(fmaxf(sc[qf][0][r], sc[qf][1][r]), fmaxf(sc[qf][2][r], sc[qf][3][r])) * SC;
        mx = fmaxf(mx, __shfl_xor(mx, 1));
        mx = fmaxf(mx, __shfl_xor(mx, 2));
        mx = fmaxf(mx, __shfl_xor(mx, 4));
        mx = fmaxf(mx, __shfl_xor(mx, 8));
        const float nm = fmaxf(mrun[qf][r], mx);
        cfac[r] = exp2f(mrun[qf][r] - nm);
        mrun[qf][r] = nm;
        float rs = 0.f;
#pragma unroll
        for (int kf = 0; kf < 4; ++kf) {
          float p = exp2f(fmaf(sc[qf][kf][r], SC, -nm));
          unsigned short pb = f2bf(p);
          Pl[wv][qf * 16 + g * 4 + r][kf * 16 + lo] = pb;
          rs += bf2f(pb);
        }
        rs += __shfl_xor(rs, 1);
        rs += __shfl_xor(rs, 2);
        rs += __shfl_xor(rs, 4);
        rs += __shfl_xor(rs, 8);
        lrun[qf][r] = lrun[qf][r] * cfac[r] + rs;
      }
      if (lo == 0) {
#pragma unroll
        for (int r = 0; r < 4; ++r) Cl[wv][qf * 16 + g * 4 + r] = cfac[r];
      }
    }
    // ---- scalar PV: lane owns dim d = l ----
    float fr[64];
#pragma unroll
    for (int jj = 0; jj < 64; ++jj)
      fr[jj] = bf2f(V[(size_t)(j0 + jj) * 64 + l]);
#pragma unroll
    for (int i = 0; i < 32; ++i) {
      float a = acc2[i] * Cl[wv][i];
#pragma unroll
      for (int jc = 0; jc < 8; ++jc) {
        short8 p8 = *reinterpret_cast<const short8*>(&Pl[wv][i][jc * 8]);
#pragma unroll
        for (int e = 0; e < 8; ++e)
          a = fmaf(bf2f((unsigned short)p8[e]), fr[jc * 8 + e], a);
      }
      acc2[i] = a;
    }
  }

  // ---- finalize ----
  if (lo == 0) {
#pragma unroll
    for (int qf = 0; qf < 2; ++qf)
#pragma unroll
      for (int r = 0; r < 4; ++r) Cl[wv][qf * 16 + g * 4 + r] = lrun[qf][r];
  }
  const int b = bh >> 4, h = bh & 15;
#pragma unroll
  for (int i = 0; i < 32; ++i) {
    const float li = Cl[wv][i];
    O[((size_t)b * 2048 + qbase + i) * 1024 + h * 64 + l] = f2bf(acc2[i] / li);
  }
}

extern "C" void kernel_launch(void* const* d_in, const int* in_sizes, int n_in,
                              void* d_out, int out_size, void* d_ws, size_t ws_size,
                              hipStream_t stream) {
  (void)in_sizes; (void)n_in; (void)out_size; (void)ws_size;
  const float* query = (const float*)d_in[0];
  const float* key_  = (const float*)d_in[1];
  const float* value = (const float*)d_in[2];
  const float* Wq = (const float*)d_in[3];
  const float* bq = (const float*)d_in[4];
  const float* Wk = (const float*)d_in[5];
  const float* bk = (const float*)d_in[6];
  const float* Wv = (const float*)d_in[7];
  const float* bv = (const float*)d_in[8];
  const float* Wo = (const float*)d_in[9];
  const float* bo = (const float*)d_in[10];

  unsigned short* ws = (unsigned short*)d_ws;
  unsigned short* Wq_bf = ws;                              // 1M elems each, contiguous
  unsigned short* Wk_bf = ws + ((size_t)1 << 20);
  unsigned short* Wv_bf = ws + ((size_t)2 << 20);
  unsigned short* Wo_bf = ws + ((size_t)3 << 20);
  unsigned short* Qh = ws + ((size_t)4 << 20);             // [4,16,2048,64] bf16
  unsigned short* Kh = Qh + ((size_t)8 << 20);
  unsigned short* Vh = Kh + ((size_t)8 << 20);             // [4,16,2048,64]
  unsigned short* Oa = Vh + ((size_t)8 << 20);             // [4,2048,1024]

  cvtw_kernel<<<2048, 256, 0, stream>>>(Wq, Wk, Wv, Wo, Wq_bf);
  dim3 gg(64, 8);
  gemm128_kernel<true><<<gg, 256, 0, stream>>>(query, Wq_bf, bq, Qh, 0);
  gemm128_kernel<true><<<gg, 256, 0, stream>>>(key_,  Wk_bf, bk, Kh, 0);
  gemm128_kernel<true><<<gg, 256, 0, stream>>>(value, Wv_bf, bv, Vh, 0);
  attn_hybrid_kernel<<<1024, 256, 0, stream>>>(Qh, Kh, Vh, Oa);
  gemm128_kernel<false><<<gg, 256, 0, stream>>>(Oa, Wo_bf, bo, d_out, 2);
}